// Round 3
// baseline (411.127 us; speedup 1.0000x reference)
//
#include <hip/hip_runtime.h>
#include <stdint.h>

// Problem constants (from reference)
#define N_CLASSES  10
#define N_TREES    4000
#define DEPTH      6
#define N_INTERNAL 63
#define N_FEATURES 128
#define BATCH      32768
#define LR         0.1f

// Kernel config.
// R15: fix R14's occupancy collapse while keeping the scalar-pipe top levels.
//  - BLOCK=512 (8 waves), SPB=64, lane==sample, 2 trees per wave per 16-tree
//    tile (wave-uniform -> depths 0-2 from s_load + cndmask, no DS).
//  - Class-split: each block does 5 classes (125 tiles); grid 1024 ->
//    4 block-works/CU over 2 resident blocks = 16 waves/CU (vs R14's 8).
//  - Scalar node loads software-pipelined one tile ahead (latency spans
//    phases A+B instead of sitting on the critical path).
// DS model: 4000 wave-tiles/CU x (6 b64*7 + 12 b32*5.8) = 446K cyc ~= 186us.
#define BLOCK       256                     // prep / fallback block
#define EBLOCK      512                     // eval block (8 waves)
#define SPB         64                      // samples per block (main kernel)
#define SAMPLES_PB  32                      // legacy geometry (prep/fallback)
#define T_TILE      16                      // trees per LDS tile (8 KB int2 nodes)
#define N_TILES     (N_TREES / T_TILE)      // 250
#define TILES_PER_CLASS ((N_TREES / N_CLASSES) / T_TILE)   // 25
#define CPB         5                       // classes per block (class-split)

// prep grid split (unchanged geometry)
#define XPOSE_BLOCKS (BATCH / SAMPLES_PB)           // 1024
#define PACK_BLOCKS  ((N_TREES * 64) / BLOCK)       // 1000

// ws layout:
//   [0, 2.048MB)        nodes by slot, interleaved int2 (feat, thr_bits), 64/tree
//   [2.048MB, 3.072MB)  leaves (64 f32/tree), class-grouped slots
//   [3.072MB, 19.85MB)  x^T: [N_FEATURES][BATCH] f32 (DMA-friendly staging)
// slot = (t%10)*400 + t/10  (class-grouped: 25-tile runs are single-class).
#define WS_NODES_BYTES  ((size_t)N_TREES * 64 * 8)
#define WS_LEAVES_BYTES ((size_t)N_TREES * 64 * 4)
#define WS_XT_BYTES     ((size_t)N_FEATURES * BATCH * 4)

// s_waitcnt immediates (gfx9): vmcnt[3:0] | expcnt<<4 | lgkmcnt<<8
// Steady state in-flight at the wait: [DMA(t), lv(t-1) x2, DMA(t+1)] ->
// vmcnt(3) drains DMA(t) only. Last tile: [DMA(t), lv x2] -> vmcnt(2).
#define WAITCNT_VM3  0x0F73
#define WAITCNT_VM2  0x0F72

// Fused prep: blocks [0,1024) transpose x into x^T; blocks [1024,2024) pack
// nodes+leaves into class-grouped slots.
__global__ void prep_kernel(const float* __restrict__ x,
                            const int* __restrict__ features,
                            const float* __restrict__ thresholds,
                            const float* __restrict__ leaves,
                            int2* __restrict__ pn, float* __restrict__ pl,
                            float* __restrict__ xt) {
    const int tid = threadIdx.x;
    if (blockIdx.x < XPOSE_BLOCKS) {
        __shared__ float tile[N_FEATURES * 33];
        const int sample0 = blockIdx.x * SAMPLES_PB;
        const float4* xg = (const float4*)(x + (size_t)sample0 * N_FEATURES);
        #pragma unroll
        for (int k = 0; k < 4; ++k) {
            int e = tid + k * BLOCK;
            int s = e >> 5, f4 = e & 31;
            float4 v = xg[e];
            int f = f4 << 2;
            tile[(f + 0) * 33 + s] = v.x;
            tile[(f + 1) * 33 + s] = v.y;
            tile[(f + 2) * 33 + s] = v.z;
            tile[(f + 3) * 33 + s] = v.w;
        }
        __syncthreads();
        #pragma unroll
        for (int k = 0; k < 4; ++k) {
            int e = tid + k * BLOCK;
            int f = e >> 3, sq = e & 7;
            float4 w;
            w.x = tile[f * 33 + 4 * sq + 0];
            w.y = tile[f * 33 + 4 * sq + 1];
            w.z = tile[f * 33 + 4 * sq + 2];
            w.w = tile[f * 33 + 4 * sq + 3];
            *(float4*)(xt + (size_t)f * BATCH + sample0 + 4 * sq) = w;
        }
    } else {
        int i = (blockIdx.x - XPOSE_BLOCKS) * BLOCK + tid;
        int t = i >> 6, n = i & 63;
        int slot = (t % N_CLASSES) * (N_TREES / N_CLASSES) + (t / N_CLASSES);
        if (n < N_INTERNAL)
            pn[slot * 64 + n] = make_int2(features[t * N_INTERNAL + n],
                                          __float_as_int(thresholds[t * N_INTERNAL + n]));
        pl[slot * 64 + n] = leaves[t * 64 + n];
    }
}

// Standalone pack (mid tier without xt space)
__global__ void pack_kernel(const int* __restrict__ features,
                            const float* __restrict__ thresholds,
                            const float* __restrict__ leaves,
                            int2* __restrict__ pn, float* __restrict__ pl) {
    int i = blockIdx.x * blockDim.x + threadIdx.x;
    int t = i >> 6, n = i & 63;
    if (t < N_TREES) {
        int slot = (t % N_CLASSES) * (N_TREES / N_CLASSES) + (t / N_CLASSES);
        if (n < N_INTERNAL)
            pn[slot * 64 + n] = make_int2(features[t * N_INTERNAL + n],
                                          __float_as_int(thresholds[t * N_INTERNAL + n]));
        pl[slot * 64 + n] = leaves[t * 64 + n];
    }
}

// CK-style addrspace casts for global_load_lds (proven R5..R12).
__device__ __forceinline__ void load_lds_16(const void* g, void* l) {
    const auto* g1 = reinterpret_cast<const __attribute__((address_space(1))) uint32_t*>(
        reinterpret_cast<uintptr_t>(g));
    auto* l3 = reinterpret_cast<__attribute__((address_space(3))) uint32_t*>(
        reinterpret_cast<uintptr_t>(l));
    __builtin_amdgcn_global_load_lds(g1, l3, 16, 0, 0);
}

template <bool XT>
__global__ __launch_bounds__(EBLOCK, 4) void gbt_eval(
    const float* __restrict__ x,        // original [BATCH][F] (XT=false path)
    const float* __restrict__ xt,       // x^T [F][BATCH]      (XT=true path)
    const int2*  __restrict__ pnodes,   // [N_TREES][64] int2, class-grouped slots
    const float* __restrict__ pleaves,  // [N_TREES][64], class-grouped slots
    const float* __restrict__ init_out, // [10]
    float*       __restrict__ out)      // [BATCH][10], written directly
{
    __shared__ float xs[N_FEATURES * SPB];              // 32 KB, transposed [f][s]
    __shared__ int2  nbuf[2][T_TILE * 64];              // 2 x 8 KB node tiles
    __shared__ float sums[SPB * CPB];                   // 1.25 KB

    const int tid  = threadIdx.x;
    const int lane = tid & 63;                          // lane == sample
    const int wv   = __builtin_amdgcn_readfirstlane(tid >> 6);  // wave 0..7, uniform
    const int sg   = blockIdx.x >> 1;                   // sample group (512)
    const int h    = blockIdx.x & 1;                    // class half (0/1)
    const int sample0 = sg * SPB;

    if (XT) {
        // Stage xs[f][64]: wave wv loads features [wv*16, wv*16+16).
        // Per 1 KB DMA: 4 feature rows x 64 samples; 16 lanes cover one row.
        #pragma unroll
        for (int q = 0; q < 4; ++q) {
            int f0 = wv * 16 + q * 4;
            const char* g = (const char*)(xt
                + (size_t)(f0 + (lane >> 4)) * BATCH + sample0 + (lane & 15) * 4);
            load_lds_16(g, (char*)xs + (size_t)f0 * SPB * 4);
        }
    } else {
        const float4* xg = (const float4*)(x + (size_t)sample0 * N_FEATURES);
        for (int e = tid; e < SPB * (N_FEATURES / 4); e += EBLOCK) {
            int s = e >> 5, f4 = e & 31;
            float4 v = xg[e];
            int f = f4 << 2;
            xs[(f + 0) * SPB + s] = v.x;
            xs[(f + 1) * SPB + s] = v.y;
            xs[(f + 2) * SPB + s] = v.z;
            xs[(f + 3) * SPB + s] = v.w;
        }
    }
    for (int i = tid; i < SPB * CPB; i += EBLOCK) sums[i] = 0.f;

    // Stage one 8 KB node tile: wave wv DMAs the 1 KB chunk holding exactly
    // its own trees {2wv, 2wv+1} -- wave-private, no per-tile barrier.
    auto stage = [&](int tile, int b) {
        const char* g = (const char*)(pnodes + (size_t)(tile * T_TILE) * 64);
        load_lds_16(g + wv * 1024 + lane * 16, (char*)&nbuf[b][0] + wv * 1024);
    };
    // Scalar-pipe load of a tile's top 7 nodes for this wave's 2 trees
    // (wave-uniform address -> s_load; consumed one iteration later).
    auto ldsn = [&](int tile, int2 sn[2][7]) {
        #pragma unroll
        for (int u = 0; u < 2; ++u) {
            const int2* tp = pnodes + (size_t)(tile * T_TILE + wv * 2 + u) * 64;
            #pragma unroll
            for (int k = 0; k < 7; ++k) sn[u][k] = tp[k];
        }
    };

    const int tile0 = h * (N_TILES / 2);        // 0 or 125
    const int tileE = tile0 + N_TILES / 2;

    stage(tile0, 0);
    int2 snc[2][7], snn[2][7];
    ldsn(tile0, snc);
    __syncthreads();   // xs is cross-wave shared: one full barrier (drains vmcnt)

    int cur = 0;
    int tile = tile0;
    for (int c = 0; c < CPB; ++c) {
        float acc = 0.f;
        float lv0 = 0.f, lv1 = 0.f;     // previous tile's leaf loads (pipelined)
        for (int t25 = 0; t25 < TILES_PER_CLASS; ++t25, ++tile) {
            const bool pre = (tile + 1 < tileE);
            if (pre) {
                stage(tile + 1, cur ^ 1);
                ldsn(tile + 1, snn);    // s_load latency hides under A+B
            }

            // ---- Phase A: depths 0-2 from SGPRs + cndmask (no DS) ----
            int o[2];
            #pragma unroll
            for (int u = 0; u < 2; ++u) {
                int2 n0 = snc[u][0], n1 = snc[u][1], n2 = snc[u][2];
                int2 n3 = snc[u][3], n4 = snc[u][4], n5 = snc[u][5], n6 = snc[u][6];
                float x0 = xs[n0.x * SPB + lane];
                int b0 = x0 > __int_as_float(n0.y);
                int2 m1 = b0 ? n2 : n1;
                float x1 = xs[m1.x * SPB + lane];
                int b1 = x1 > __int_as_float(m1.y);
                int2 mA = b0 ? n5 : n3;
                int2 mB = b0 ? n6 : n4;
                int2 m2 = b1 ? mB : mA;
                float x2 = xs[m2.x * SPB + lane];
                int b2 = x2 > __int_as_float(m2.y);
                o[u] = 7 + 4 * b0 + 2 * b1 + b2;    // node entering depth 3
            }

            // Drain this tile's DMA only (vmcnt literal-constant call sites).
            if (pre) {
                __builtin_amdgcn_s_waitcnt(WAITCNT_VM3);
            } else {
                __builtin_amdgcn_s_waitcnt(WAITCNT_VM2);
            }

            // Consume PREVIOUS tile's leaves (older than DMA(t+1): this wait
            // does not drain the prefetch).
            acc += lv0 + lv1;

            // ---- Phase B: depths 3-5, LDS gather (the only DS node reads) --
            #pragma unroll
            for (int u = 0; u < 2; ++u) {
                const int2* nb = &nbuf[cur][(wv * 2 + u) * 64];
                int oo = o[u];
                #pragma unroll
                for (int d = 3; d < DEPTH; ++d) {
                    int2 a = nb[oo];                // ds_read_b64
                    float xv = xs[a.x * SPB + lane];
                    oo = 2 * oo + 1 + (xv > __int_as_float(a.y) ? 1 : 0);
                }
                const size_t slot = (size_t)(tile * T_TILE + wv * 2 + u);
                float l = pleaves[slot * 64 + (oo - N_INTERNAL)];
                if (u == 0) lv0 = l; else lv1 = l;
            }

            if (pre) {
                #pragma unroll
                for (int u = 0; u < 2; ++u)
                    #pragma unroll
                    for (int k = 0; k < 7; ++k) snc[u][k] = snn[u][k];
            }
            cur ^= 1;
        }
        acc += lv0 + lv1;               // flush the class's final pair
        atomicAdd(&sums[lane * CPB + c], acc);
    }
    __syncthreads();

    // Each block owns (its samples x its 5 classes): plain coalesced stores.
    for (int e = tid; e < SPB * CPB; e += EBLOCK) {
        int s = e / CPB, k = e - s * CPB;
        out[(size_t)(sample0 + s) * N_CLASSES + h * CPB + k] =
            init_out[h * CPB + k] + LR * sums[s * CPB + k];
    }
}

// Fallback (ws too small even for nodes+leaves): direct-global gather,
// single block per 32 samples owns all trees (no atomics on out).
__global__ __launch_bounds__(BLOCK, 8) void gbt_eval_global(
    const float* __restrict__ x,
    const int*   __restrict__ features,
    const float* __restrict__ thresholds,
    const float* __restrict__ leaf_values,
    const float* __restrict__ init_out,
    float*       __restrict__ out)
{
    __shared__ float xs[N_FEATURES * SAMPLES_PB];
    __shared__ float sums[SAMPLES_PB * N_CLASSES];
    const int tid = threadIdx.x;
    const int sample0 = blockIdx.x * SAMPLES_PB;
    {
        const float4* xg = (const float4*)(x + (size_t)sample0 * N_FEATURES);
        for (int e = tid; e < SAMPLES_PB * (N_FEATURES / 4); e += BLOCK) {
            int s = e >> 5, f4 = e & 31;
            float4 v = xg[e];
            int f = f4 << 2;
            xs[(f + 0) * SAMPLES_PB + s] = v.x;
            xs[(f + 1) * SAMPLES_PB + s] = v.y;
            xs[(f + 2) * SAMPLES_PB + s] = v.z;
            xs[(f + 3) * SAMPLES_PB + s] = v.w;
        }
    }
    for (int i = tid; i < SAMPLES_PB * N_CLASSES; i += BLOCK) sums[i] = 0.f;
    __syncthreads();
    const int sLocal = tid & (SAMPLES_PB - 1);
    const int j = tid >> 5;
    const int TPT = N_TREES / 8;
    const int t0 = j * TPT;
    float acc[N_CLASSES];
    #pragma unroll
    for (int k = 0; k < N_CLASSES; ++k) acc[k] = 0.f;
    for (int i = 0; i < TPT; i += N_CLASSES) {
        const int tt = t0 + i;
        int idx[N_CLASSES];
        #pragma unroll
        for (int u = 0; u < N_CLASSES; ++u) idx[u] = 0;
        #pragma unroll
        for (int d = 0; d < DEPTH; ++d) {
            #pragma unroll
            for (int u = 0; u < N_CLASSES; ++u) {
                int base = (tt + u) * N_INTERNAL + idx[u];
                float xv = xs[features[base] * SAMPLES_PB + sLocal];
                idx[u] = 2 * idx[u] + 1 + (xv > thresholds[base] ? 1 : 0);
            }
        }
        #pragma unroll
        for (int u = 0; u < N_CLASSES; ++u)
            acc[u] += leaf_values[(size_t)(tt + u) * 64 + idx[u] - N_INTERNAL];
    }
    #pragma unroll
    for (int k = 0; k < N_CLASSES; ++k)
        atomicAdd(&sums[sLocal * N_CLASSES + k], acc[k]);
    __syncthreads();
    for (int e = tid; e < SAMPLES_PB * N_CLASSES; e += BLOCK) {
        int s = e / N_CLASSES, k = e - s * N_CLASSES;
        out[(size_t)(sample0 + s) * N_CLASSES + k] = init_out[k] + LR * sums[e];
    }
}

extern "C" void kernel_launch(void* const* d_in, const int* in_sizes, int n_in,
                              void* d_out, int out_size, void* d_ws, size_t ws_size,
                              hipStream_t stream) {
    const float* x          = (const float*)d_in[0];
    const int*   features   = (const int*)d_in[1];
    const float* thresholds = (const float*)d_in[2];
    const float* leafvals   = (const float*)d_in[3];
    const float* init_out   = (const float*)d_in[4];
    float*       out        = (float*)d_out;

    // grid: 512 sample-groups x 2 class-halves = 1024 blocks of 512 threads
    // -> 4 block-works/CU over 2 resident blocks (16 waves/CU), no tail.
    const int grid = (BATCH / SPB) * 2;

    if (ws_size >= WS_NODES_BYTES + WS_LEAVES_BYTES + WS_XT_BYTES) {
        int2*  pn = (int2*)d_ws;
        float* pl = (float*)((char*)d_ws + WS_NODES_BYTES);
        float* xt = (float*)((char*)d_ws + WS_NODES_BYTES + WS_LEAVES_BYTES);
        prep_kernel<<<XPOSE_BLOCKS + PACK_BLOCKS, BLOCK, 0, stream>>>(
            x, features, thresholds, leafvals, pn, pl, xt);
        gbt_eval<true><<<grid, EBLOCK, 0, stream>>>(x, xt, pn, pl, init_out, out);
    } else if (ws_size >= WS_NODES_BYTES + WS_LEAVES_BYTES) {
        int2*  pn = (int2*)d_ws;
        float* pl = (float*)((char*)d_ws + WS_NODES_BYTES);
        int n = N_TREES * 64;
        pack_kernel<<<(n + 255) / 256, 256, 0, stream>>>(features, thresholds,
                                                         leafvals, pn, pl);
        gbt_eval<false><<<grid, EBLOCK, 0, stream>>>(x, nullptr, pn, pl, init_out, out);
    } else {
        gbt_eval_global<<<BATCH / SAMPLES_PB, BLOCK, 0, stream>>>(
            x, features, thresholds, leafvals, init_out, out);
    }
}